// Round 8
// baseline (194.604 us; speedup 1.0000x reference)
//
#include <hip/hip_runtime.h>

typedef float f32x4 __attribute__((ext_vector_type(4)));
typedef long i64;

#define FP8_MAX 448.0f
#define AS1 __attribute__((address_space(1)))
#define AS3 __attribute__((address_space(3)))

// ---------------------------------------------------------------------------
// Activation quant: per (row, 128-elem K-block): s = max|x|/448, q = fp8(x/s).
// Writes xq [M][K] fp8 bytes and xst TRANSPOSED scales [K/128][M].
// ---------------------------------------------------------------------------
__global__ __launch_bounds__(256) void act_quant_k(const float* __restrict__ x,
                                                   unsigned char* __restrict__ xq,
                                                   float* __restrict__ xst,
                                                   int M, int K) {
    const int t   = threadIdx.x;
    const int qb  = blockIdx.x * 8 + (t >> 5);   // global 128-block id
    const int l32 = t & 31;
    const int row = qb >> 5;                     // K/128 == 32 blocks per row
    const int kb  = qb & 31;
    const size_t base = (size_t)row * K + (size_t)kb * 128 + (size_t)l32 * 4;

    float4 v = *(const float4*)(x + base);
    float am = fmaxf(fmaxf(fabsf(v.x), fabsf(v.y)), fmaxf(fabsf(v.z), fabsf(v.w)));
#pragma unroll
    for (int off = 1; off < 32; off <<= 1)
        am = fmaxf(am, __shfl_xor(am, off, 64));

    const float s = am / FP8_MAX;                // fp32 IEEE div, matches reference
    const float q0 = v.x / s, q1 = v.y / s, q2 = v.z / s, q3 = v.w / s;
    int p = __builtin_amdgcn_cvt_pk_fp8_f32(q0, q1, 0, false);
    p     = __builtin_amdgcn_cvt_pk_fp8_f32(q2, q3, p, true);
    *(int*)(xq + base) = p;
    if (l32 == 0) xst[(size_t)kb * M + row] = s;
}

// ---------------------------------------------------------------------------
// Weight fp32 -> fp8 byte conversion (values already on the e4m3 grid: exact).
// ---------------------------------------------------------------------------
__global__ __launch_bounds__(256) void wq_cvt_k(const float* __restrict__ w,
                                                unsigned char* __restrict__ wq) {
    const size_t i = ((size_t)blockIdx.x * 256 + threadIdx.x) * 4;
    float4 v = *(const float4*)(w + i);
    int p = __builtin_amdgcn_cvt_pk_fp8_f32(v.x, v.y, 0, false);
    p     = __builtin_amdgcn_cvt_pk_fp8_f32(v.z, v.w, p, true);
    *(int*)(wq + i) = p;
}

// ---------------------------------------------------------------------------
// 128x256-tile fp8 block-dequant GEMM, ONE 32-MFMA phase per K-step (BK=64).
// 8 waves (2Mx4N), per-wave 64x64 = 4x4 frags of 16x16x32 fp8 MFMA.
// Per K-step: {ds_read pa/pb/scales -> stage next+2 K-step (ring-3) ->
// barrier -> 32 MFMA (z4-start, ks-chained) -> fold accM += q*sc ->
// counted VMCNT -> barrier}. Counted vmcnt (4/3 alternating, 0 only in the
// peeled tail) gives every staged load ~2 K-steps of flight time.
// Slot count halved vs the 8-phase 256^2 variant: per-slot overhead (2
// barriers, ds segment, fold tail) amortizes over 2x the MFMA work.
//
// LDS swizzle (both-sides, rule 21): logical [rows][64B]; physical byte =
// row*64 + (col ^ (((row>>1)&3)<<4)). Staging keeps the LDS dest LINEAR and
// pre-swizzles the per-lane GLOBAL source column; ds_read applies the XOR.
//
// vmcnt bookkeeping (per wave): batch(k even) = [S(k/2+1),A,B,B] = 4,
// batch(k odd) = [A,B,B] = 3. At end of K-step k, outstanding =
// batch(k-1)+batch(k); retire batch(k-1) -> VMCNT(|batch(k)|): even->4,
// odd->3. Prologue stages K0+K1 (7), VMCNT(3). Tail: k=62 VMCNT(0).
// ---------------------------------------------------------------------------
__global__ __launch_bounds__(512, 2) void gemm_fp8_blk(
    const unsigned char* __restrict__ Aq,   // [M][K] fp8
    const unsigned char* __restrict__ Bq,   // [N][K] fp8
    const float* __restrict__ xst,          // [K/128][M] act scales (transposed)
    const float* __restrict__ wsc,          // [N/128][K/128] weight scales
    float* __restrict__ C, int M, int N, int K) {
    __shared__ unsigned char As[3 * 8192];   // ring-3 [128 rows x 64 B]
    __shared__ unsigned char Bs[3 * 16384];  // ring-3 [256 rows x 64 B]
    __shared__ float Ss[256];                // 2 scale slots x 128 rows

    const int t    = threadIdx.x;
    const int lane = t & 63;
    const int wave = t >> 6;            // 0..7
    const int wr   = wave >> 2;         // wave row (0..1) -> rows wr*64
    const int wc   = wave & 3;          // wave col (0..3) -> cols wc*64
    const int bm   = blockIdx.y * 128;
    const int bn   = blockIdx.x * 256;

    // staging: 512 threads x 16B = 8KB per issue. A: 1 issue (128 rows).
    // B: 2 issues (rows 0-127, 128-255).
    const int srow   = t >> 2;          // 0..127
    const int scolsw = (((t & 3) ^ ((t >> 3) & 3)) << 4);   // pre-swizzled src col
    const unsigned char* gA = Aq + (size_t)(bm + srow) * K + scolsw;
    const unsigned char* gB = Bq + (size_t)(bn + srow) * K + scolsw;
    const float* gS = xst + bm + ((wave & 1) << 6) + lane;  // + kb*M per stage
    const int ldsoff = wave << 10;      // wave-uniform LDS base (+ lane*16 by HW)
    const int sSoff  = (wave & 1) << 8; // 256B halves; waves 2-7 dup 0-1: benign

    // fragment read addressing (swizzled)
    const int r15 = lane & 15;
    const int g   = lane >> 4;                    // k-group 0..3
    const int sX  = (r15 >> 1) & 3;               // (row>>1)&3, row-const per lane
    const int sub = (g & 1) << 3;                 // 0 or 8 bytes within 16B unit
    const int c0  = g >> 1;                       // logical col16 at ks=0
    const int pc0 = ((c0 ^ sX) << 4) + sub;
    const int pc1 = (((c0 + 2) ^ sX) << 4) + sub;
    const int aBase = (wr * 64 + r15) * 64;       // + m<<10 per frag
    const int bBase = (wc * 64 + r15) * 64;       // + n<<10 per frag
    const int ssBase = wr * 64 + (g << 2);        // + m*16 (float idx in slot)

    const unsigned char* AsG = As;
    const unsigned char* BsG = Bs;
    const float* wscp = wsc + ((bn >> 7) + (wc >> 1)) * 32;  // wave-uniform

#define STG_A(AO, KS)                                                           \
    __builtin_amdgcn_global_load_lds(                                           \
        (const AS1 void*)(gA + ((size_t)(KS) << 6)),                            \
        (AS3 void*)(As + (AO) + ldsoff), 16, 0, 0)
#define STG_B(BO, KS, H)                                                        \
    __builtin_amdgcn_global_load_lds(                                           \
        (const AS1 void*)(gB + (size_t)(H) * 128 * K + ((size_t)(KS) << 6)),    \
        (AS3 void*)(Bs + (BO) + (H) * 8192 + ldsoff), 16, 0, 0)
#define STG_S(KB)                                                               \
    __builtin_amdgcn_global_load_lds(                                           \
        (const AS1 void*)(gS + (size_t)(KB) * M),                               \
        (AS3 void*)((unsigned char*)Ss + (((KB) & 1) << 9) + sSoff), 4, 0, 0)
#define VMCNT(N_) asm volatile("s_waitcnt vmcnt(" #N_ ")" ::: "memory")

#define KSTEP(AO, BO, WA, WB, KNEW, SCKB, DOS, ENDW) do {                       \
    i64 pa[4][2], pb[4][2];                                                     \
    _Pragma("unroll")                                                           \
    for (int m = 0; m < 4; ++m) {                                               \
        pa[m][0] = *(const i64*)(AsG + (AO) + aBase + (m << 10) + pc0);         \
        pa[m][1] = *(const i64*)(AsG + (AO) + aBase + (m << 10) + pc1);         \
    }                                                                           \
    _Pragma("unroll")                                                           \
    for (int n = 0; n < 4; ++n) {                                               \
        pb[n][0] = *(const i64*)(BsG + (BO) + bBase + (n << 10) + pc0);         \
        pb[n][1] = *(const i64*)(BsG + (BO) + bBase + (n << 10) + pc1);         \
    }                                                                           \
    f32x4 sc[4];                                                                \
    _Pragma("unroll")                                                           \
    for (int m = 0; m < 4; ++m)                                                 \
        sc[m] = (*(const f32x4*)(Ss + slB + ssBase + (m << 4))) * wsv_it;       \
    if (DOS) {                                                                  \
        if ((SCKB) >= 0) STG_S(SCKB);                                           \
        STG_A(WA, KNEW);                                                        \
        STG_B(WB, KNEW, 0); STG_B(WB, KNEW, 1);                                 \
    }                                                                           \
    __builtin_amdgcn_s_barrier();                                               \
    __builtin_amdgcn_s_setprio(1);                                              \
    f32x4 q[4][4];                                                              \
    _Pragma("unroll")                                                           \
    for (int m = 0; m < 4; ++m)                                                 \
        _Pragma("unroll")                                                       \
        for (int n = 0; n < 4; ++n)                                             \
            q[m][n] = __builtin_amdgcn_mfma_f32_16x16x32_fp8_fp8(               \
                pa[m][0], pb[n][0], z4, 0, 0, 0);                               \
    _Pragma("unroll")                                                           \
    for (int m = 0; m < 4; ++m)                                                 \
        _Pragma("unroll")                                                       \
        for (int n = 0; n < 4; ++n)                                             \
            q[m][n] = __builtin_amdgcn_mfma_f32_16x16x32_fp8_fp8(               \
                pa[m][1], pb[n][1], q[m][n], 0, 0, 0);                          \
    __builtin_amdgcn_s_setprio(0);                                              \
    _Pragma("unroll")                                                           \
    for (int m = 0; m < 4; ++m)                                                 \
        _Pragma("unroll")                                                       \
        for (int n = 0; n < 4; ++n)                                             \
            accM[m][n] += q[m][n] * sc[m];                                      \
    ENDW;                                                                       \
    __builtin_amdgcn_s_barrier();                                               \
    asm volatile("" ::: "memory");                                              \
} while (0)

    f32x4 accM[4][4] = {};
    const f32x4 z4 = {0.f, 0.f, 0.f, 0.f};

    // ring-3 byte offsets (As stride 8192, Bs stride 16384)
    int a0 = 0, a1 = 8192, a2 = 16384;
    int b0 = 0, b1 = 16384, b2 = 32768;

    // prologue: [S0, A0, B0h0, B0h1, A1, B1h0, B1h1]; retire first 4.
    STG_S(0);
    STG_A(a0, 0); STG_B(b0, 0, 0); STG_B(b0, 0, 1);
    STG_A(a1, 1); STG_B(b1, 1, 0); STG_B(b1, 1, 1);
    VMCNT(3);
    __builtin_amdgcn_s_barrier();
    asm volatile("" ::: "memory");

#pragma unroll 1
    for (int kb = 0; kb < 31; ++kb) {
        const float wsv_it = wscp[kb];
        const int slB = (kb & 1) << 7;   // float offset of scale slot
        // k = 2kb (even): stage S(kb+1) + K-step 2kb+2 into (a2,b2)
        KSTEP(a0, b0, a2, b2, 2 * kb + 2, kb + 1, 1, VMCNT(4));
        // k = 2kb+1 (odd): stage K-step 2kb+3 into (a0,b0)
        KSTEP(a1, b1, a0, b0, 2 * kb + 3, -1, 1, VMCNT(3));
        const int ta = a0; a0 = a2; a2 = a1; a1 = ta;
        const int tb = b0; b0 = b2; b2 = b1; b1 = tb;
    }
    {   // peeled tail kb=31: K-steps 62 (a0,b0) and 63 (a1,b1); no staging
        const float wsv_it = wscp[31];
        const int slB = (31 & 1) << 7;
        KSTEP(a0, b0, 0, 0, 0, -1, 0, VMCNT(0));
        KSTEP(a1, b1, 0, 0, 0, -1, 0, ((void)0));
    }

    // C write: row = g*4 + reg within frag, col = r15 (verified C/D layout)
    const int cm = bm + wr * 64 + (g << 2);
    const int cn = bn + wc * 64 + r15;
#pragma unroll
    for (int m = 0; m < 4; ++m)
#pragma unroll
        for (int n = 0; n < 4; ++n) {
            float* cp = C + (size_t)(cm + m * 16) * N + (cn + n * 16);
#pragma unroll
            for (int r = 0; r < 4; ++r) cp[(size_t)r * N] = accM[m][n][r];
        }
#undef STG_A
#undef STG_B
#undef STG_S
#undef VMCNT
#undef KSTEP
}

extern "C" void kernel_launch(void* const* d_in, const int* in_sizes, int n_in,
                              void* d_out, int out_size, void* d_ws, size_t ws_size,
                              hipStream_t stream) {
    const float* x   = (const float*)d_in[0];   // [4096][4096] fp32
    const float* wqf = (const float*)d_in[1];   // [4096][4096] fp32 (fp8-grid values)
    const float* wsc = (const float*)d_in[2];   // [32][32] fp32
    float* out = (float*)d_out;

    const int M = 4096, N = 4096, K = 4096;

    unsigned char* xq  = (unsigned char*)d_ws;                       // 16 MB
    unsigned char* wq8 = (unsigned char*)d_ws + (size_t)M * K;       // 16 MB
    float* xst = (float*)((unsigned char*)d_ws + (size_t)M * K + (size_t)N * K); // 512 KB

    act_quant_k<<<M * (K / 128) / 8, 256, 0, stream>>>(x, xq, xst, M, K);
    wq_cvt_k<<<(N / 4) * (K / 256), 256, 0, stream>>>(wqf, wq8);
    dim3 grid(N / 256, M / 128);
    gemm_fp8_blk<<<grid, 512, 0, stream>>>(xq, wq8, xst, wsc, out, M, N, K);
}

// Round 10
// 126.457 us; speedup vs baseline: 1.5389x; 1.5389x over previous
//
#include <hip/hip_runtime.h>

typedef float f32x4 __attribute__((ext_vector_type(4)));
typedef int   i32x4 __attribute__((ext_vector_type(4)));
typedef int   i32x8 __attribute__((ext_vector_type(8)));

#define FP8_MAX 448.0f
#define AS1 __attribute__((address_space(1)))
#define AS3 __attribute__((address_space(3)))

// ---------------------------------------------------------------------------
// Activation quant: per (row, 128-elem K-block): s = max|x|/448, q = fp8(x/s).
// Writes xq [M][K] fp8 bytes and xst TRANSPOSED scales [K/128][M].
// ---------------------------------------------------------------------------
__global__ __launch_bounds__(256) void act_quant_k(const float* __restrict__ x,
                                                   unsigned char* __restrict__ xq,
                                                   float* __restrict__ xst,
                                                   int M, int K) {
    const int t   = threadIdx.x;
    const int qb  = blockIdx.x * 8 + (t >> 5);   // global 128-block id
    const int l32 = t & 31;
    const int row = qb >> 5;                     // K/128 == 32 blocks per row
    const int kb  = qb & 31;
    const size_t base = (size_t)row * K + (size_t)kb * 128 + (size_t)l32 * 4;

    float4 v = *(const float4*)(x + base);
    float am = fmaxf(fmaxf(fabsf(v.x), fabsf(v.y)), fmaxf(fabsf(v.z), fabsf(v.w)));
#pragma unroll
    for (int off = 1; off < 32; off <<= 1)
        am = fmaxf(am, __shfl_xor(am, off, 64));

    const float s = am / FP8_MAX;                // fp32 IEEE div, matches reference
    const float q0 = v.x / s, q1 = v.y / s, q2 = v.z / s, q3 = v.w / s;
    int p = __builtin_amdgcn_cvt_pk_fp8_f32(q0, q1, 0, false);
    p     = __builtin_amdgcn_cvt_pk_fp8_f32(q2, q3, p, true);
    *(int*)(xq + base) = p;
    if (l32 == 0) xst[(size_t)kb * M + row] = s;
}

// ---------------------------------------------------------------------------
// Weight fp32 -> fp8 byte conversion (values already on the e4m3 grid: exact).
// ---------------------------------------------------------------------------
__global__ __launch_bounds__(256) void wq_cvt_k(const float* __restrict__ w,
                                                unsigned char* __restrict__ wq) {
    const size_t i = ((size_t)blockIdx.x * 256 + threadIdx.x) * 4;
    float4 v = *(const float4*)(w + i);
    int p = __builtin_amdgcn_cvt_pk_fp8_f32(v.x, v.y, 0, false);
    p     = __builtin_amdgcn_cvt_pk_fp8_f32(v.z, v.w, p, true);
    *(int*)(wq + i) = p;
}

// ---------------------------------------------------------------------------
// 256x256-tile fp8 block-dequant GEMM on mfma_scale_f32_16x16x128_f8f6f4
// (HW scales = 1.0 -> exact fp8 dot over K=128 = exactly one quant block).
// 8 waves (2Mx4N), per-wave 128x64 = 8m x 4n frags; 32 mfma_scale per K-step.
// K-step = 128; 32 steps; double-buffered LDS; ONE barrier + one vmcnt(0)
// drain per K-step (drain is issued ~2500 cyc after the 9 staged loads).
// Fold once per frag per K-step: accM[m][n] += q * (a_s[m] * w_s).
//
// LDS layout: [256 rows][128 B] per operand per buffer. Swizzle (both-sides,
// rule 21): phys_col16 = col16 ^ (row & 7). Staging keeps the LDS dest
// LINEAR and pre-swizzles the per-lane GLOBAL source column; ds_read applies
// the same XOR (involution). Frag read = 2 x b128 -> i32x8 (32 consecutive
// k-bytes per lane at k = (lane>>4)*32, the natural f8f6f4 operand layout).
// ---------------------------------------------------------------------------
__global__ __launch_bounds__(512, 2) void gemm_fp8_blk(
    const unsigned char* __restrict__ Aq,   // [M][K] fp8
    const unsigned char* __restrict__ Bq,   // [N][K] fp8
    const float* __restrict__ xst,          // [K/128][M] act scales (transposed)
    const float* __restrict__ wsc,          // [N/128][K/128] weight scales
    float* __restrict__ C, int M, int N, int K) {
    __shared__ unsigned char As[2][32768];  // [buf][256 rows x 128 B]
    __shared__ unsigned char Bs[2][32768];
    __shared__ float Ss[2][256];            // act scales, 2-slot ring

    const int t    = threadIdx.x;
    const int lane = t & 63;
    const int wave = t >> 6;            // 0..7
    const int wr   = wave >> 2;         // wave row (0..1) -> rows wr*128
    const int wc   = wave & 3;          // wave col (0..3) -> cols wc*64
    const int bm   = blockIdx.y * 256;
    const int bn   = blockIdx.x * 256;

    // staging: 512 threads x 16B = 8KB = 64 rows x 128B per issue; 4/op/K-step
    const int srow   = t >> 3;          // 0..63
    const int scolsw = (((t & 7) ^ ((t >> 3) & 7)) << 4);   // pre-swizzled src col
    const unsigned char* gA = Aq + (size_t)(bm + srow) * K + scolsw;
    const unsigned char* gB = Bq + (size_t)(bn + srow) * K + scolsw;
    const float* gS = xst + bm + ((wave & 3) << 6) + lane;  // + kb*M per stage
    const int ldsoff = wave << 10;      // wave-uniform LDS base (+ lane*16 by HW)
    const int sSoff  = (wave & 3) << 8; // waves 4-7 duplicate 0-3 (same data)

    // fragment read addressing (swizzled): lane holds k = g*32 + 0..31
    const int r15 = lane & 15;
    const int g   = lane >> 4;                    // k-chunk 0..3
    const int km  = r15 & 7;                      // row swizzle key
    const int pc0 = (((2 * g) ^ km) << 4);        // first 16B unit
    const int pc1 = pc0 ^ 16;                     // second 16B unit
    const int aBase = (wr * 128 + r15) << 7;      // + m*2048 per frag
    const int bBase = (wc * 64 + r15) << 7;       // + n*2048 per frag
    const int ssB   = wr * 128 + (g << 2);        // float idx into Ss slot

    const float* wscp = wsc + (((bn + wc * 64) >> 7) << 5);  // wave-uniform row

#define STG_A(BUF, KB, I)                                                       \
    __builtin_amdgcn_global_load_lds(                                           \
        (const AS1 void*)(gA + (size_t)(I) * 64 * K + ((size_t)(KB) << 7)),     \
        (AS3 void*)(&As[BUF][0] + (I) * 8192 + ldsoff), 16, 0, 0)
#define STG_B(BUF, KB, I)                                                       \
    __builtin_amdgcn_global_load_lds(                                           \
        (const AS1 void*)(gB + (size_t)(I) * 64 * K + ((size_t)(KB) << 7)),     \
        (AS3 void*)(&Bs[BUF][0] + (I) * 8192 + ldsoff), 16, 0, 0)
#define STG_S(KB)                                                               \
    __builtin_amdgcn_global_load_lds(                                           \
        (const AS1 void*)(gS + (size_t)(KB) * M),                               \
        (AS3 void*)((unsigned char*)&Ss[(KB) & 1][0] + sSoff), 4, 0, 0)
#define VMCNT0() asm volatile("s_waitcnt vmcnt(0)" ::: "memory")

#define RD8(PTR, RB) ({                                                         \
    i32x4 lo_ = *(const i32x4*)((PTR) + (RB) + pc0);                            \
    i32x4 hi_ = *(const i32x4*)((PTR) + (RB) + pc1);                            \
    __builtin_shufflevector(lo_, hi_, 0, 1, 2, 3, 4, 5, 6, 7); })

    f32x4 accM[8][4] = {};
    const f32x4 z4 = {0.f, 0.f, 0.f, 0.f};

    // prologue: stage K-step 0 (scale + 4A + 4B), drain, sync.
    STG_S(0);
#pragma unroll
    for (int i = 0; i < 4; ++i) { STG_A(0, 0, i); STG_B(0, 0, i); }
    VMCNT0();
    __builtin_amdgcn_s_barrier();
    asm volatile("" ::: "memory");

#pragma unroll 1
    for (int kb = 0; kb < 32; ++kb) {
        const int buf = kb & 1;
        // stage next K-step into the other buffer (early issue: ~2500 cyc cover)
        if (kb < 31) {
            STG_S(kb + 1);
#pragma unroll
            for (int i = 0; i < 4; ++i) { STG_A(buf ^ 1, kb + 1, i); STG_B(buf ^ 1, kb + 1, i); }
        }
        const float wsv = wscp[kb];
        const unsigned char* ap = &As[buf][0];
        const unsigned char* bp = &Bs[buf][0];
        const float* sp = &Ss[buf][0];

        i32x8 pb[4];
#pragma unroll
        for (int n = 0; n < 4; ++n) pb[n] = RD8(bp, bBase + (n << 11));

#pragma unroll
        for (int h = 0; h < 2; ++h) {
            i32x8 pa[4];
            f32x4 sc[4];
#pragma unroll
            for (int mm = 0; mm < 4; ++mm) {
                pa[mm] = RD8(ap, aBase + ((h * 4 + mm) << 11));
                sc[mm] = (*(const f32x4*)(sp + ssB + ((h * 4 + mm) << 4))) * wsv;
            }
            __builtin_amdgcn_s_setprio(1);
#pragma unroll
            for (int mm = 0; mm < 4; ++mm)
#pragma unroll
                for (int n = 0; n < 4; ++n) {
                    f32x4 q = __builtin_amdgcn_mfma_scale_f32_16x16x128_f8f6f4(
                        pa[mm], pb[n], z4, 0, 0,      // fmt A=fp8, B=fp8
                        0, 0x7F7F7F7F,                // scale A = 1.0 (e8m0 127)
                        0, 0x7F7F7F7F);               // scale B = 1.0
                    accM[h * 4 + mm][n] += q * sc[mm];
                }
            __builtin_amdgcn_s_setprio(0);
        }
        VMCNT0();                      // staged loads for kb+1 have landed
        __builtin_amdgcn_s_barrier();  // everyone done reading buf
        asm volatile("" ::: "memory");
    }

    // C write: row = g*4 + reg within frag, col = r15 (verified C/D layout)
    const int cm = bm + wr * 128 + (g << 2);
    const int cn = bn + wc * 64 + r15;
#pragma unroll
    for (int m = 0; m < 8; ++m)
#pragma unroll
        for (int n = 0; n < 4; ++n) {
            float* cp = C + (size_t)(cm + m * 16) * N + (cn + n * 16);
#pragma unroll
            for (int r = 0; r < 4; ++r) cp[(size_t)r * N] = accM[m][n][r];
        }
#undef STG_A
#undef STG_B
#undef STG_S
#undef VMCNT0
#undef RD8
}

extern "C" void kernel_launch(void* const* d_in, const int* in_sizes, int n_in,
                              void* d_out, int out_size, void* d_ws, size_t ws_size,
                              hipStream_t stream) {
    const float* x   = (const float*)d_in[0];   // [4096][4096] fp32
    const float* wqf = (const float*)d_in[1];   // [4096][4096] fp32 (fp8-grid values)
    const float* wsc = (const float*)d_in[2];   // [32][32] fp32
    float* out = (float*)d_out;

    const int M = 4096, N = 4096, K = 4096;

    unsigned char* xq  = (unsigned char*)d_ws;                       // 16 MB
    unsigned char* wq8 = (unsigned char*)d_ws + (size_t)M * K;       // 16 MB
    float* xst = (float*)((unsigned char*)d_ws + (size_t)M * K + (size_t)N * K); // 512 KB

    act_quant_k<<<M * (K / 128) / 8, 256, 0, stream>>>(x, xq, xst, M, K);
    wq_cvt_k<<<(N / 4) * (K / 256), 256, 0, stream>>>(wqf, wq8);
    dim3 grid(N / 256, M / 256);
    gemm_fp8_blk<<<grid, 512, 0, stream>>>(xq, wq8, xst, wsc, out, M, N, K);
}